// Round 3
// baseline (32.987 us; speedup 1.0000x reference)
//
#include <hip/hip_runtime.h>

// out[b,o] = (rowsum(x)[b] + rowsum(w)[o]) * bias[o]
// B=8192, IN=2048, OUT=2048, all float32.
//
// Schedule: kernel A: wsb[o] = rowsum(w)[o] * bias[o]       (16 MiB read)
//           kernel B: per x-row (one WAVE per row, no LDS/barrier):
//                     reduce row -> xs; out[b,:] = xs*bias + wsb  (64R + 64W MiB)
// Touch-once streams (x, w, out) use nontemporal loads/stores; bias/wsb cached.

#define B_DIM 8192
#define IN_DIM 2048
#define OUT_DIM 2048

typedef float f32x4 __attribute__((ext_vector_type(4)));

__device__ __forceinline__ float butterfly_reduce(float s) {
    #pragma unroll
    for (int off = 32; off; off >>= 1)
        s += __shfl_xor(s, off, 64);
    return s;   // result in all 64 lanes
}

// One wave per weight row; 4 waves (4 rows) per block. 512 blocks.
__global__ __launch_bounds__(256) void wsb_kernel(const float* __restrict__ w,
                                                  const float* __restrict__ bias,
                                                  float* __restrict__ wsb) {
    const int wave = threadIdx.x >> 6;
    const int lane = threadIdx.x & 63;
    const int row  = (blockIdx.x << 2) + wave;            // 0 .. OUT_DIM-1
    const f32x4* src4 = reinterpret_cast<const f32x4*>(w + (size_t)row * IN_DIM);

    f32x4 v[8];
    #pragma unroll
    for (int k = 0; k < 8; ++k)
        v[k] = __builtin_nontemporal_load(&src4[lane + (k << 6)]);
    float s = 0.f;
    #pragma unroll
    for (int k = 0; k < 8; ++k)
        s += (v[k].x + v[k].y) + (v[k].z + v[k].w);
    s = butterfly_reduce(s);
    if (lane == 0)
        wsb[row] = s * bias[row];
}

// One wave per x row; 4 waves (4 rows) per block. 2048 blocks.
__global__ __launch_bounds__(256) void fused_row_kernel(const float* __restrict__ x,
                                                        const float* __restrict__ bias,
                                                        const float* __restrict__ wsb,
                                                        f32x4* __restrict__ out4) {
    const int wave = threadIdx.x >> 6;
    const int lane = threadIdx.x & 63;
    const int row  = (blockIdx.x << 2) + wave;            // 0 .. B_DIM-1
    const f32x4* src4  = reinterpret_cast<const f32x4*>(x + (size_t)row * IN_DIM);
    const f32x4* bias4 = reinterpret_cast<const f32x4*>(bias);
    const f32x4* wsb4  = reinterpret_cast<const f32x4*>(wsb);

    f32x4 v[8];
    #pragma unroll
    for (int k = 0; k < 8; ++k)
        v[k] = __builtin_nontemporal_load(&src4[lane + (k << 6)]);
    float s = 0.f;
    #pragma unroll
    for (int k = 0; k < 8; ++k)
        s += (v[k].x + v[k].y) + (v[k].z + v[k].w);
    const float xs = butterfly_reduce(s);                 // all lanes

    f32x4* orow = out4 + (size_t)row * (OUT_DIM / 4);
    #pragma unroll
    for (int k = 0; k < 8; ++k) {
        const int i = lane + (k << 6);
        const f32x4 bi = bias4[i];        // L2-resident broadcast
        const f32x4 ws = wsb4[i];
        f32x4 o;
        o.x = fmaf(xs, bi.x, ws.x);
        o.y = fmaf(xs, bi.y, ws.y);
        o.z = fmaf(xs, bi.z, ws.z);
        o.w = fmaf(xs, bi.w, ws.w);
        __builtin_nontemporal_store(o, &orow[i]);
    }
}

extern "C" void kernel_launch(void* const* d_in, const int* in_sizes, int n_in,
                              void* d_out, int out_size, void* d_ws, size_t ws_size,
                              hipStream_t stream) {
    const float* x    = (const float*)d_in[0];   // [8192, 2048]
    const float* w    = (const float*)d_in[1];   // [2048, 2048]
    const float* bias = (const float*)d_in[2];   // [2048]
    float* out = (float*)d_out;                  // [8192, 2048]
    float* wsb = (float*)d_ws;                   // 2048 floats

    wsb_kernel<<<OUT_DIM / 4, 256, 0, stream>>>(w, bias, wsb);
    fused_row_kernel<<<B_DIM / 4, 256, 0, stream>>>(x, bias, wsb, (f32x4*)out);
}